// Round 9
// baseline (132.312 us; speedup 1.0000x reference)
//
#include <hip/hip_runtime.h>
#include <math.h>

// CapsuleLayer dynamic routing, fully fused: one block per batch element.
// B=256, O=10, U=36, S=32, E=16, F=8, N=1152, 3 routing iterations.
//
// u_hat is never materialized:
//   v_pre[o,e]  = sum_{u,f} W[o,u,e,f] * cx[o,u,f],  cx[o,u,f] = sum_s c[o,n]*x[n,f]
//   b[o,n]     += sum_f x[n,f] * wv[o,u,f],          wv[o,u,f] = sum_e W[o,u,e,f]*v[o,e]
//
// Round-9 = round-8 with the W-hoist spill fixed. Round 8's 24-float4 W hoist
// got spilled to scratch (VGPR=128, WRITE_SIZE 21.7MB) yet STILL beat
// L2-streaming (62->53us) — confirming shared-W L2 latency/contention as a
// real cost. This round makes the hoist land in actual VGPRs:
//  - amdgpu_waves_per_eu(2,2): occupancy is structurally 2 waves/SIMD
//    (1 block/CU, 8 waves), so pinning is free and gives the allocator the
//    full 256-VGPR budget.
//  - W rows loaded UNCONDITIONALLY (clamped role for l>=60): conditionally-
//    initialized long live ranges are a spill trigger.
//
// Structure (round 7): 512 threads = 8 waves = 2/SIMD, per-wave-uniform phase
// maps, cx split over s-halves (shfl_xor(1) combine), 2 rows/thread + third
// row on 128 SIMD-balanced threads.
//
// LDS swizzles: u-stride is 32 rows -> 32*pitch = 0 mod 32 banks for any pitch:
//   x row (u,s), 16B half h' -> word u*256 + ((2s + h' + u)&63)*4
//   c[o][n]                  -> word o*1152 + u*32 + ((s+u)&31)

namespace {

constexpr int kO = 10;
constexpr int kU = 36;
constexpr int kS = 32;
constexpr int kE = 16;
constexpr int kF = 8;
constexpr int kN = kU * kS;    // 1152
constexpr int kIters = 3;
constexpr int kThreads = 512;  // 8 waves, 2 per SIMD
constexpr int kPitch = 12;     // padded (o,u)-row pitch for s_cx/s_wv

__global__ void
__attribute__((amdgpu_flat_work_group_size(512, 512), amdgpu_waves_per_eu(2, 2)))
caps_routing_kernel(const float* __restrict__ xg,
                    const float* __restrict__ Wg,
                    float* __restrict__ outg) {
  __shared__ float s_x[kN * kF];            // 36.9 KB, swizzled
  __shared__ float s_c[kO * kN];            // 46.1 KB, swizzled
  __shared__ float s_cx[kO * kU * kPitch];  // 17.3 KB
  __shared__ float s_wv[kO * kU * kPitch];  // 17.3 KB
  __shared__ float s_vp[kO * kE * 3];       //  1.9 KB
  __shared__ float s_sx[kU * kF];           //  1.2 KB (sum_s x, for it=0)
  // total ~121 KB

  const int t = threadIdx.x;
  const int w = t >> 6;
  const int l = t & 63;
  const int b = blockIdx.x;

  float xr0[kF], xr1[kF], xr2[kF];
  float br0[kO], br1[kO], br2[kO];
  const bool has3 = (w < 4) && (l < 32);  // third row: 128 threads, SIMD-balanced

  const int u0r = t >> 5;          // rows 0..511    -> u 0..15
  const int s0r = t & 31;
  const int rot0 = (s0r + u0r) & 31;
  const int u1r = 16 + (t >> 5);   // rows 512..1023 -> u 16..31
  const int rot1 = (s0r + u1r) & 31;
  const int u2r = 32 + w;          // rows 1024..1151 -> u 32..35
  const int rot2 = (l + u2r) & 31;

  // v_pre role (computed UNCONDITIONALLY, clamped for l>=60 so W loads are
  // always-defined valid addresses — avoids conditional-init spill trigger)
  const bool vp_act = (l < 60);
  const int vp_i = w * 60 + (l < 60 ? l : 59);
  const int vp_o = vp_i / 48;
  const int vp_r = vp_i - vp_o * 48;
  const int vp_e = vp_r / 3;
  const int vp_uc = vp_r - vp_e * 3;
  const int vp_u0 = vp_uc * 12;

  // ---- iteration-invariant W rows for v_pre: 24 float4s in registers ----
#define DECLW(I) float4 wA##I, wB##I;
  DECLW(0) DECLW(1) DECLW(2) DECLW(3) DECLW(4) DECLW(5)
  DECLW(6) DECLW(7) DECLW(8) DECLW(9) DECLW(10) DECLW(11)
#undef DECLW
  {
    const float* wrow = Wg + ((size_t)(vp_o * kU + vp_u0) * kE + vp_e) * kF;
#define LOADW(I)                                                              \
  {                                                                           \
    const float4* p_ = reinterpret_cast<const float4*>(wrow + (I) * kE * kF); \
    wA##I = p_[0];                                                            \
    wB##I = p_[1];                                                            \
  }
    LOADW(0) LOADW(1) LOADW(2) LOADW(3) LOADW(4) LOADW(5)
    LOADW(6) LOADW(7) LOADW(8) LOADW(9) LOADW(10) LOADW(11)
#undef LOADW
  }

  // ---- prologue: load rows -> regs + swizzled LDS; half-wave butterfly sx ----
#define STAGEROW(XR, N, U, S)                                                 \
  {                                                                           \
    const float4* src_ =                                                      \
        reinterpret_cast<const float4*>(xg + ((size_t)b * kN + (N)) * kF);    \
    const float4 a0_ = src_[0];                                               \
    const float4 a1_ = src_[1];                                               \
    XR[0] = a0_.x; XR[1] = a0_.y; XR[2] = a0_.z; XR[3] = a0_.w;               \
    XR[4] = a1_.x; XR[5] = a1_.y; XR[6] = a1_.z; XR[7] = a1_.w;               \
    const int sl0_ = (((S) << 1) + (U)) & 63;                                 \
    const int sl1_ = (((S) << 1) + 1 + (U)) & 63;                             \
    *reinterpret_cast<float4*>(&s_x[(U) * 256 + sl0_ * 4]) = a0_;             \
    *reinterpret_cast<float4*>(&s_x[(U) * 256 + sl1_ * 4]) = a1_;             \
    float4 r0_ = a0_, r1_ = a1_;                                              \
    _Pragma("unroll")                                                         \
    for (int m_ = 1; m_ <= 16; m_ <<= 1) {                                    \
      r0_.x += __shfl_xor(r0_.x, m_); r0_.y += __shfl_xor(r0_.y, m_);         \
      r0_.z += __shfl_xor(r0_.z, m_); r0_.w += __shfl_xor(r0_.w, m_);         \
      r1_.x += __shfl_xor(r1_.x, m_); r1_.y += __shfl_xor(r1_.y, m_);         \
      r1_.z += __shfl_xor(r1_.z, m_); r1_.w += __shfl_xor(r1_.w, m_);         \
    }                                                                         \
    if ((S) == 0) {                                                           \
      *reinterpret_cast<float4*>(&s_sx[(U) * kF + 0]) = r0_;                  \
      *reinterpret_cast<float4*>(&s_sx[(U) * kF + 4]) = r1_;                  \
    }                                                                         \
  }

  STAGEROW(xr0, t, u0r, s0r)
  STAGEROW(xr1, t + 512, u1r, s0r)
  if (has3) STAGEROW(xr2, 1024 + w * 32 + l, u2r, l)
#undef STAGEROW
#pragma unroll
  for (int o = 0; o < kO; ++o) { br0[o] = 0.f; br1[o] = 0.f; br2[o] = 0.f; }
  __syncthreads();

  for (int it = 0; it <= kIters; ++it) {
    // ---- cx[o][u][f] = sum_s c[o][n]*x[n][f] ----
    // thread (op,u,h): o-pair op, s-half h; 360 active spread as l<46 per wave.
    // Pairing: i = w*46+l, 46 even -> lane parity == i parity, so (h0,h1) of
    // each (op,u) are adjacent lanes; combined via __shfl_xor(1).
    if (it > 0) {
      if (l < 46) {
        const int i = w * 46 + l;
        if (i < 360) {
          const int op  = i / 72;
          const int rem = i - op * 72;
          const int u   = rem >> 1;
          const int h   = rem & 1;
          const int o0  = op * 2, o1 = o0 + 1;
          float4 p00 = make_float4(0.f, 0.f, 0.f, 0.f);
          float4 p01 = make_float4(0.f, 0.f, 0.f, 0.f);
          float4 p10 = make_float4(0.f, 0.f, 0.f, 0.f);
          float4 p11 = make_float4(0.f, 0.f, 0.f, 0.f);
#pragma unroll 4
          for (int j = 0; j < 16; ++j) {
            const int s   = h * 16 + j;
            const int rot = (s + u) & 31;
            const int sl0 = ((s << 1) + u) & 63;
            const int sl1 = ((s << 1) + 1 + u) & 63;
            const float4 xa =
                *reinterpret_cast<const float4*>(&s_x[u * 256 + sl0 * 4]);
            const float4 xb =
                *reinterpret_cast<const float4*>(&s_x[u * 256 + sl1 * 4]);
            const float c0 = s_c[o0 * kN + u * 32 + rot];
            const float c1 = s_c[o1 * kN + u * 32 + rot];
            p00.x += c0 * xa.x; p00.y += c0 * xa.y; p00.z += c0 * xa.z; p00.w += c0 * xa.w;
            p01.x += c0 * xb.x; p01.y += c0 * xb.y; p01.z += c0 * xb.z; p01.w += c0 * xb.w;
            p10.x += c1 * xa.x; p10.y += c1 * xa.y; p10.z += c1 * xa.z; p10.w += c1 * xa.w;
            p11.x += c1 * xb.x; p11.y += c1 * xb.y; p11.z += c1 * xb.z; p11.w += c1 * xb.w;
          }
          // combine the two s-halves (adjacent lanes, same (op,u))
          p00.x += __shfl_xor(p00.x, 1); p00.y += __shfl_xor(p00.y, 1);
          p00.z += __shfl_xor(p00.z, 1); p00.w += __shfl_xor(p00.w, 1);
          p01.x += __shfl_xor(p01.x, 1); p01.y += __shfl_xor(p01.y, 1);
          p01.z += __shfl_xor(p01.z, 1); p01.w += __shfl_xor(p01.w, 1);
          p10.x += __shfl_xor(p10.x, 1); p10.y += __shfl_xor(p10.y, 1);
          p10.z += __shfl_xor(p10.z, 1); p10.w += __shfl_xor(p10.w, 1);
          p11.x += __shfl_xor(p11.x, 1); p11.y += __shfl_xor(p11.y, 1);
          p11.z += __shfl_xor(p11.z, 1); p11.w += __shfl_xor(p11.w, 1);
          if (h == 0) {
            float4* d = reinterpret_cast<float4*>(&s_cx[(o0 * kU + u) * kPitch]);
            d[0] = p00; d[1] = p01;
          } else {
            float4* d = reinterpret_cast<float4*>(&s_cx[(o1 * kU + u) * kPitch]);
            d[0] = p10; d[1] = p11;
          }
        }
      }
      __syncthreads();
    }

    // ---- v_pre partials: thread=(o,e,uc), 480 active; W from REGISTERS ----
    if (vp_act) {
      float accA = 0.f, accB = 0.f;
      if (it == 0) {
#define VPSTEP0(I)                                                            \
  {                                                                           \
    const float4* cp_ =                                                       \
        reinterpret_cast<const float4*>(&s_sx[(vp_u0 + (I)) * kF]);           \
    const float4 c0_ = cp_[0];                                                \
    const float4 c1_ = cp_[1];                                                \
    accA += wA##I.x * c0_.x + wA##I.y * c0_.y + wA##I.z * c0_.z + wA##I.w * c0_.w; \
    accB += wB##I.x * c1_.x + wB##I.y * c1_.y + wB##I.z * c1_.z + wB##I.w * c1_.w; \
  }
        VPSTEP0(0) VPSTEP0(1) VPSTEP0(2) VPSTEP0(3) VPSTEP0(4) VPSTEP0(5)
        VPSTEP0(6) VPSTEP0(7) VPSTEP0(8) VPSTEP0(9) VPSTEP0(10) VPSTEP0(11)
#undef VPSTEP0
        accA = (accA + accB) * 0.1f;
      } else {
#define VPSTEP(I)                                                             \
  {                                                                           \
    const float4* cp_ = reinterpret_cast<const float4*>(                      \
        &s_cx[(vp_o * kU + vp_u0 + (I)) * kPitch]);                           \
    const float4 c0_ = cp_[0];                                                \
    const float4 c1_ = cp_[1];                                                \
    accA += wA##I.x * c0_.x + wA##I.y * c0_.y + wA##I.z * c0_.z + wA##I.w * c0_.w; \
    accB += wB##I.x * c1_.x + wB##I.y * c1_.y + wB##I.z * c1_.z + wB##I.w * c1_.w; \
  }
        VPSTEP(0) VPSTEP(1) VPSTEP(2) VPSTEP(3) VPSTEP(4) VPSTEP(5)
        VPSTEP(6) VPSTEP(7) VPSTEP(8) VPSTEP(9) VPSTEP(10) VPSTEP(11)
#undef VPSTEP
        accA += accB;
      }
      s_vp[(vp_o * kE + vp_e) * 3 + vp_uc] = accA;
    }
    __syncthreads();

    // ---- final pass: squash + store output, done ----
    if (it == kIters) {
      if (t < kO * kE) {
        const float vsum = s_vp[t * 3 + 0] + s_vp[t * 3 + 1] + s_vp[t * 3 + 2];
        float n2 = vsum * vsum;
#pragma unroll
        for (int m = 1; m <= 8; m <<= 1) n2 += __shfl_xor(n2, m);
        const float scale = sqrtf(n2) / (1.f + n2);
        outg[(size_t)b * kO * kE + t] = vsum * scale;
      }
      break;
    }

    // ---- wv[o][u][f] = sum_e W[o][u][e][f]*v[o][e]; 360 active as l<45 ----
    // squash folded in; v rebuilt into named float4s (broadcast s_vp reads)
    if (l < 45) {
      const int i = w * 45 + l;  // 0..359
      const int o = i / 36;
      const int u = i - o * 36;
#define SUMVP(E_) (s_vp[(o * kE + (E_)) * 3 + 0] + \
                   s_vp[(o * kE + (E_)) * 3 + 1] + \
                   s_vp[(o * kE + (E_)) * 3 + 2])
      float4 va, vb, vc, vd;
      va.x = SUMVP(0);  va.y = SUMVP(1);  va.z = SUMVP(2);  va.w = SUMVP(3);
      vb.x = SUMVP(4);  vb.y = SUMVP(5);  vb.z = SUMVP(6);  vb.w = SUMVP(7);
      vc.x = SUMVP(8);  vc.y = SUMVP(9);  vc.z = SUMVP(10); vc.w = SUMVP(11);
      vd.x = SUMVP(12); vd.y = SUMVP(13); vd.z = SUMVP(14); vd.w = SUMVP(15);
#undef SUMVP
      const float n2 =
          va.x * va.x + va.y * va.y + va.z * va.z + va.w * va.w +
          vb.x * vb.x + vb.y * vb.y + vb.z * vb.z + vb.w * vb.w +
          vc.x * vc.x + vc.y * vc.y + vc.z * vc.z + vc.w * vc.w +
          vd.x * vd.x + vd.y * vd.y + vd.z * vd.z + vd.w * vd.w;
      const float scale = sqrtf(n2) / (1.f + n2);
      const float* wbase = Wg + (size_t)(o * kU + u) * kE * kF;
      float4 acc0 = make_float4(0.f, 0.f, 0.f, 0.f);
      float4 acc1 = make_float4(0.f, 0.f, 0.f, 0.f);
#define WSTEP(VE_, E_)                                                        \
  {                                                                           \
    const float4* wp = reinterpret_cast<const float4*>(wbase + (E_) * kF);    \
    const float4 w0 = wp[0];                                                  \
    const float4 w1 = wp[1];                                                  \
    const float ve = (VE_) * scale;                                           \
    acc0.x += ve * w0.x; acc0.y += ve * w0.y;                                 \
    acc0.z += ve * w0.z; acc0.w += ve * w0.w;                                 \
    acc1.x += ve * w1.x; acc1.y += ve * w1.y;                                 \
    acc1.z += ve * w1.z; acc1.w += ve * w1.w;                                 \
  }
      WSTEP(va.x, 0)  WSTEP(va.y, 1)  WSTEP(va.z, 2)  WSTEP(va.w, 3)
      WSTEP(vb.x, 4)  WSTEP(vb.y, 5)  WSTEP(vb.z, 6)  WSTEP(vb.w, 7)
      WSTEP(vc.x, 8)  WSTEP(vc.y, 9)  WSTEP(vc.z, 10) WSTEP(vc.w, 11)
      WSTEP(vd.x, 12) WSTEP(vd.y, 13) WSTEP(vd.z, 14) WSTEP(vd.w, 15)
#undef WSTEP
      float4* d = reinterpret_cast<float4*>(&s_wv[(o * kU + u) * kPitch]);
      d[0] = acc0;
      d[1] = acc1;
    }
    __syncthreads();

    // ---- b[o,n] += x[n,:].wv[o,u,:]; thread-local softmax over o; write c ----
#define BSMROW(XR, BR, U, ROT)                                                \
  {                                                                           \
    float mx_ = -3.4e38f;                                                     \
    _Pragma("unroll")                                                         \
    for (int o_ = 0; o_ < kO; ++o_) {                                         \
      const float4* wp_ =                                                     \
          reinterpret_cast<const float4*>(&s_wv[(o_ * kU + (U)) * kPitch]);   \
      const float4 w0_ = wp_[0];                                              \
      const float4 w1_ = wp_[1];                                              \
      BR[o_] += w0_.x * XR[0] + w0_.y * XR[1] + w0_.z * XR[2] + w0_.w * XR[3] \
              + w1_.x * XR[4] + w1_.y * XR[5] + w1_.z * XR[6] + w1_.w * XR[7];\
      mx_ = fmaxf(mx_, BR[o_]);                                               \
    }                                                                         \
    float ex_[kO];                                                            \
    float sum_ = 0.f;                                                         \
    _Pragma("unroll")                                                         \
    for (int o_ = 0; o_ < kO; ++o_) {                                         \
      ex_[o_] = __expf(BR[o_] - mx_);                                         \
      sum_ += ex_[o_];                                                        \
    }                                                                         \
    const float inv_ = 1.f / sum_;                                            \
    _Pragma("unroll")                                                         \
    for (int o_ = 0; o_ < kO; ++o_)                                           \
      s_c[o_ * kN + (U) * 32 + (ROT)] = ex_[o_] * inv_;                       \
  }
    BSMROW(xr0, br0, u0r, rot0)
    BSMROW(xr1, br1, u1r, rot1)
    if (has3) BSMROW(xr2, br2, u2r, rot2)
#undef BSMROW
    __syncthreads();
  }
}

}  // namespace

extern "C" void kernel_launch(void* const* d_in, const int* in_sizes, int n_in,
                              void* d_out, int out_size, void* d_ws, size_t ws_size,
                              hipStream_t stream) {
  const float* x = (const float*)d_in[0];  // (B, 1152, 8) fp32
  const float* W = (const float*)d_in[1];  // (10, 36, 16, 8) fp32
  float* out = (float*)d_out;              // (B, 10, 16) fp32

  const int batch = in_sizes[0] / (kN * kF);  // 256
  caps_routing_kernel<<<dim3(batch), dim3(kThreads), 0, stream>>>(x, W, out);
}

// Round 10
// 121.822 us; speedup vs baseline: 1.0861x; 1.0861x over previous
//
#include <hip/hip_runtime.h>
#include <math.h>

// CapsuleLayer dynamic routing, fully fused: one block per batch element.
// B=256, O=10, U=36, S=32, E=16, F=8, N=1152, 3 routing iterations.
//
// u_hat is never materialized:
//   v_pre[o,e]  = sum_{u,f} W[o,u,e,f] * cx[o,u,f],  cx[o,u,f] = sum_s c[o,n]*x[n,f]
//   b[o,n]     += sum_f x[n,f] * wv[o,u,f],          wv[o,u,f] = sum_e W[o,u,e,f]*v[o,e]
//
// Round-10: occupancy doubling. Rounds 2-9 showed a latency-bound 14-phase
// barrier chain stuck at ~20% VALUBusy with 8 waves/CU (2/SIMD); the register
// allocator pins VGPR at 128 (= 4 waves/EU target) and spills any W-hoist.
// So: 1024-thread block = 16 waves = 4/SIMD (allocator's own target), LDS
// ~119 KB = still 1 block/CU, grid 256 = 1 block/CU. Occupancy 8->16 waves.
// Phases re-mapped wider + per-wave-uniform:
//   cx   : 720 roles (o,u,s-half), 46/44 per wave (even pair bases so
//          shfl_xor(1) partners hold the same (o,u))
//   v_pre: 640 roles (o,e,uc: 4 u-chunks of 9), in-wave 4-lane butterfly
//          finalizes v -> s_v[o*16+e] single value (kills s_vp re-reduce)
//   wv   : 720 roles (o,u,e-half), shfl_xor(1) combine, squash folded in
//   bsm  : 1 row/thread + 2nd row on t<128
// W streams from L2 (no hoist: stays under 128 VGPR, no spill).
//
// LDS swizzles (proven r5/r7): u-stride is 32 rows -> 32*pitch = 0 mod 32
// banks for any pitch, so rotate slots by u:
//   x row (u,s), 16B half h' -> word u*256 + ((2s + h' + u)&63)*4
//   c[o][n]                  -> word o*1152 + u*32 + ((s+u)&31)

namespace {

constexpr int kO = 10;
constexpr int kU = 36;
constexpr int kS = 32;
constexpr int kE = 16;
constexpr int kF = 8;
constexpr int kN = kU * kS;     // 1152
constexpr int kIters = 3;
constexpr int kThreads = 1024;  // 16 waves, 4 per SIMD
constexpr int kPitch = 12;      // padded (o,u)-row pitch for s_cx/s_wv

__launch_bounds__(kThreads, 4)  // 4 waves/EU -> VGPR cap 128 (allocator's target)
__global__ void caps_routing_kernel(const float* __restrict__ xg,
                                    const float* __restrict__ Wg,
                                    float* __restrict__ outg) {
  __shared__ float s_x[kN * kF];            // 36.9 KB, swizzled
  __shared__ float s_c[kO * kN];            // 46.1 KB, swizzled
  __shared__ float s_cx[kO * kU * kPitch];  // 17.3 KB
  __shared__ float s_wv[kO * kU * kPitch];  // 17.3 KB
  __shared__ float s_v[kO * kE];            //  0.6 KB (finalized v_pre)
  __shared__ float s_sx[kU * kF];           //  1.2 KB (sum_s x, for it=0)
  // total ~119.4 KB -> 1 block/CU

  const int t = threadIdx.x;
  const int w = t >> 6;
  const int l = t & 63;
  const int b = blockIdx.x;

  float xr0[kF], xr1[kF];
  float br0[kO], br1[kO];
  const bool has2 = (t < 128);  // second row: u 32..35

  const int u0r = t >> 5;          // rows 0..1023 -> u 0..31
  const int s0r = t & 31;
  const int rot0 = (s0r + u0r) & 31;
  const int u1r = 32 + (t >> 5);   // rows 1024..1151 (t<128) -> u 32..35
  const int rot1 = (s0r + u1r) & 31;

  // ---- prologue: load rows -> regs + swizzled LDS; half-wave butterfly sx ----
#define STAGEROW(XR, N, U, S)                                                 \
  {                                                                           \
    const float4* src_ =                                                      \
        reinterpret_cast<const float4*>(xg + ((size_t)b * kN + (N)) * kF);    \
    const float4 a0_ = src_[0];                                               \
    const float4 a1_ = src_[1];                                               \
    XR[0] = a0_.x; XR[1] = a0_.y; XR[2] = a0_.z; XR[3] = a0_.w;               \
    XR[4] = a1_.x; XR[5] = a1_.y; XR[6] = a1_.z; XR[7] = a1_.w;               \
    const int sl0_ = (((S) << 1) + (U)) & 63;                                 \
    const int sl1_ = (((S) << 1) + 1 + (U)) & 63;                             \
    *reinterpret_cast<float4*>(&s_x[(U) * 256 + sl0_ * 4]) = a0_;             \
    *reinterpret_cast<float4*>(&s_x[(U) * 256 + sl1_ * 4]) = a1_;             \
    float4 r0_ = a0_, r1_ = a1_;                                              \
    _Pragma("unroll")                                                         \
    for (int m_ = 1; m_ <= 16; m_ <<= 1) {                                    \
      r0_.x += __shfl_xor(r0_.x, m_); r0_.y += __shfl_xor(r0_.y, m_);         \
      r0_.z += __shfl_xor(r0_.z, m_); r0_.w += __shfl_xor(r0_.w, m_);         \
      r1_.x += __shfl_xor(r1_.x, m_); r1_.y += __shfl_xor(r1_.y, m_);         \
      r1_.z += __shfl_xor(r1_.z, m_); r1_.w += __shfl_xor(r1_.w, m_);         \
    }                                                                         \
    if ((S) == 0) {                                                           \
      *reinterpret_cast<float4*>(&s_sx[(U) * kF + 0]) = r0_;                  \
      *reinterpret_cast<float4*>(&s_sx[(U) * kF + 4]) = r1_;                  \
    }                                                                         \
  }

  STAGEROW(xr0, t, u0r, s0r)
  if (has2) STAGEROW(xr1, 1024 + t, u1r, s0r)
#undef STAGEROW
#pragma unroll
  for (int o = 0; o < kO; ++o) { br0[o] = 0.f; br1[o] = 0.f; }
  __syncthreads();

  for (int it = 0; it <= kIters; ++it) {
    // ---- cx[o][u][f] = sum_s c[o][n]*x[n][f]; 720 roles (o,u,h) ----
    // wave w: base = 45w + (w&1) (always even), cnt = 46/44 -> pair (h0,h1)
    // of each (o,u) sits at lanes {l, l^1}; combined via __shfl_xor(1).
    if (it > 0) {
      const int base = w * 45 + (w & 1);
      const int cnt = 46 - ((w & 1) << 1);
      if (l < cnt) {
        const int i = base + l;  // 0..719
        const int o = i / 72;
        const int rem = i - o * 72;
        const int u = rem >> 1;
        const int h = rem & 1;
        float4 p0 = make_float4(0.f, 0.f, 0.f, 0.f);
        float4 p1 = make_float4(0.f, 0.f, 0.f, 0.f);
#pragma unroll 4
        for (int j = 0; j < 16; ++j) {
          const int s = h * 16 + j;
          const int rot = (s + u) & 31;
          const int sl0 = ((s << 1) + u) & 63;
          const int sl1 = ((s << 1) + 1 + u) & 63;
          const float4 xa =
              *reinterpret_cast<const float4*>(&s_x[u * 256 + sl0 * 4]);
          const float4 xb =
              *reinterpret_cast<const float4*>(&s_x[u * 256 + sl1 * 4]);
          const float c0 = s_c[o * kN + u * 32 + rot];
          p0.x += c0 * xa.x; p0.y += c0 * xa.y; p0.z += c0 * xa.z; p0.w += c0 * xa.w;
          p1.x += c0 * xb.x; p1.y += c0 * xb.y; p1.z += c0 * xb.z; p1.w += c0 * xb.w;
        }
        p0.x += __shfl_xor(p0.x, 1); p0.y += __shfl_xor(p0.y, 1);
        p0.z += __shfl_xor(p0.z, 1); p0.w += __shfl_xor(p0.w, 1);
        p1.x += __shfl_xor(p1.x, 1); p1.y += __shfl_xor(p1.y, 1);
        p1.z += __shfl_xor(p1.z, 1); p1.w += __shfl_xor(p1.w, 1);
        if (h == 0) {
          float4* d = reinterpret_cast<float4*>(&s_cx[(o * kU + u) * kPitch]);
          d[0] = p0;
          d[1] = p1;
        }
      }
      __syncthreads();
    }

    // ---- v_pre: 640 roles (o,e,uc), uc = 4 chunks of 9 u's ----
    // base = 40w (mult of 4): quad lanes {4k..4k+3} hold uc 0..3 of one (o,e);
    // xor(1)+xor(2) butterfly finalizes; lane uc==0 writes s_v[o*16+e].
    if (l < 40) {
      const int i = w * 40 + l;  // 0..639
      const int g = i >> 2;      // (o,e) 0..159
      const int uc = i & 3;
      const int o = g >> 4;
      const int e = g & 15;
      const int u0 = uc * 9;
      float accA = 0.f, accB = 0.f;
      const float* wrow = Wg + ((size_t)(o * kU + u0) * kE + e) * kF;
      if (it == 0) {
#pragma unroll
        for (int j = 0; j < 9; ++j) {
          const float4* wp = reinterpret_cast<const float4*>(wrow);
          const float4 w0 = wp[0];
          const float4 w1 = wp[1];
          const float4* cp =
              reinterpret_cast<const float4*>(&s_sx[(u0 + j) * kF]);
          const float4 c0 = cp[0];
          const float4 c1 = cp[1];
          accA += w0.x * c0.x + w0.y * c0.y + w0.z * c0.z + w0.w * c0.w;
          accB += w1.x * c1.x + w1.y * c1.y + w1.z * c1.z + w1.w * c1.w;
          wrow += kE * kF;
        }
        accA = (accA + accB) * 0.1f;
      } else {
#pragma unroll
        for (int j = 0; j < 9; ++j) {
          const float4* wp = reinterpret_cast<const float4*>(wrow);
          const float4 w0 = wp[0];
          const float4 w1 = wp[1];
          const float4* cp = reinterpret_cast<const float4*>(
              &s_cx[(o * kU + u0 + j) * kPitch]);
          const float4 c0 = cp[0];
          const float4 c1 = cp[1];
          accA += w0.x * c0.x + w0.y * c0.y + w0.z * c0.z + w0.w * c0.w;
          accB += w1.x * c1.x + w1.y * c1.y + w1.z * c1.z + w1.w * c1.w;
          wrow += kE * kF;
        }
        accA += accB;
      }
      accA += __shfl_xor(accA, 1);
      accA += __shfl_xor(accA, 2);
      if ((l & 3) == 0) s_v[g] = accA;
    }
    __syncthreads();

    // ---- final pass: squash + store output, done ----
    if (it == kIters) {
      if (t < kO * kE) {
        const float vsum = s_v[t];
        float n2 = vsum * vsum;
#pragma unroll
        for (int m = 1; m <= 8; m <<= 1) n2 += __shfl_xor(n2, m);
        const float scale = sqrtf(n2) / (1.f + n2);
        outg[(size_t)b * kO * kE + t] = vsum * scale;
      }
      break;
    }

    // ---- wv[o][u][f] = sum_e W[o][u][e][f]*v[o][e]; 720 roles (o,u,eh) ----
    // squash folded in (each thread computes scale from the 16 s_v values);
    // e-halves combined via shfl_xor(1); eh==0 lane writes.
    {
      const int base = w * 45 + (w & 1);
      const int cnt = 46 - ((w & 1) << 1);
      if (l < cnt) {
        const int i = base + l;  // 0..719
        const int g = i >> 1;    // (o,u) 0..359
        const int eh = i & 1;
        const int o = g / 36;
        const int u = g - o * 36;
        float4 va, vb, vc, vd;
        va.x = s_v[o * kE + 0];  va.y = s_v[o * kE + 1];
        va.z = s_v[o * kE + 2];  va.w = s_v[o * kE + 3];
        vb.x = s_v[o * kE + 4];  vb.y = s_v[o * kE + 5];
        vb.z = s_v[o * kE + 6];  vb.w = s_v[o * kE + 7];
        vc.x = s_v[o * kE + 8];  vc.y = s_v[o * kE + 9];
        vc.z = s_v[o * kE + 10]; vc.w = s_v[o * kE + 11];
        vd.x = s_v[o * kE + 12]; vd.y = s_v[o * kE + 13];
        vd.z = s_v[o * kE + 14]; vd.w = s_v[o * kE + 15];
        const float n2 =
            va.x * va.x + va.y * va.y + va.z * va.z + va.w * va.w +
            vb.x * vb.x + vb.y * vb.y + vb.z * vb.z + vb.w * vb.w +
            vc.x * vc.x + vc.y * vc.y + vc.z * vc.z + vc.w * vc.w +
            vd.x * vd.x + vd.y * vd.y + vd.z * vd.z + vd.w * vd.w;
        const float scale = sqrtf(n2) / (1.f + n2);
        // this thread's e-half: eh==0 -> va,vb (e 0..7); eh==1 -> vc,vd (e 8..15)
        const float4 h0 = eh ? vc : va;
        const float4 h1 = eh ? vd : vb;
        const float* wbase =
            Wg + ((size_t)(o * kU + u) * kE + eh * 8) * kF;
        float4 acc0 = make_float4(0.f, 0.f, 0.f, 0.f);
        float4 acc1 = make_float4(0.f, 0.f, 0.f, 0.f);
#define WSTEP(VE_, K_)                                                        \
  {                                                                           \
    const float4* wp = reinterpret_cast<const float4*>(wbase + (K_) * kF);    \
    const float4 w0 = wp[0];                                                  \
    const float4 w1 = wp[1];                                                  \
    const float ve = (VE_) * scale;                                           \
    acc0.x += ve * w0.x; acc0.y += ve * w0.y;                                 \
    acc0.z += ve * w0.z; acc0.w += ve * w0.w;                                 \
    acc1.x += ve * w1.x; acc1.y += ve * w1.y;                                 \
    acc1.z += ve * w1.z; acc1.w += ve * w1.w;                                 \
  }
        WSTEP(h0.x, 0) WSTEP(h0.y, 1) WSTEP(h0.z, 2) WSTEP(h0.w, 3)
        WSTEP(h1.x, 4) WSTEP(h1.y, 5) WSTEP(h1.z, 6) WSTEP(h1.w, 7)
#undef WSTEP
        acc0.x += __shfl_xor(acc0.x, 1); acc0.y += __shfl_xor(acc0.y, 1);
        acc0.z += __shfl_xor(acc0.z, 1); acc0.w += __shfl_xor(acc0.w, 1);
        acc1.x += __shfl_xor(acc1.x, 1); acc1.y += __shfl_xor(acc1.y, 1);
        acc1.z += __shfl_xor(acc1.z, 1); acc1.w += __shfl_xor(acc1.w, 1);
        if (eh == 0) {
          float4* d = reinterpret_cast<float4*>(&s_wv[(o * kU + u) * kPitch]);
          d[0] = acc0;
          d[1] = acc1;
        }
      }
      __syncthreads();
    }

    // ---- b[o,n] += x[n,:].wv[o,u,:]; thread-local softmax over o; write c ----
#define BSMROW(XR, BR, U, ROT)                                                \
  {                                                                           \
    float mx_ = -3.4e38f;                                                     \
    _Pragma("unroll")                                                         \
    for (int o_ = 0; o_ < kO; ++o_) {                                         \
      const float4* wp_ =                                                     \
          reinterpret_cast<const float4*>(&s_wv[(o_ * kU + (U)) * kPitch]);   \
      const float4 w0_ = wp_[0];                                              \
      const float4 w1_ = wp_[1];                                              \
      BR[o_] += w0_.x * XR[0] + w0_.y * XR[1] + w0_.z * XR[2] + w0_.w * XR[3] \
              + w1_.x * XR[4] + w1_.y * XR[5] + w1_.z * XR[6] + w1_.w * XR[7];\
      mx_ = fmaxf(mx_, BR[o_]);                                               \
    }                                                                         \
    float ex_[kO];                                                            \
    float sum_ = 0.f;                                                         \
    _Pragma("unroll")                                                         \
    for (int o_ = 0; o_ < kO; ++o_) {                                         \
      ex_[o_] = __expf(BR[o_] - mx_);                                         \
      sum_ += ex_[o_];                                                        \
    }                                                                         \
    const float inv_ = 1.f / sum_;                                            \
    _Pragma("unroll")                                                         \
    for (int o_ = 0; o_ < kO; ++o_)                                           \
      s_c[o_ * kN + (U) * 32 + (ROT)] = ex_[o_] * inv_;                       \
  }
    BSMROW(xr0, br0, u0r, rot0)
    if (has2) BSMROW(xr1, br1, u1r, rot1)
#undef BSMROW
    __syncthreads();
  }
}

}  // namespace

extern "C" void kernel_launch(void* const* d_in, const int* in_sizes, int n_in,
                              void* d_out, int out_size, void* d_ws, size_t ws_size,
                              hipStream_t stream) {
  const float* x = (const float*)d_in[0];  // (B, 1152, 8) fp32
  const float* W = (const float*)d_in[1];  // (10, 36, 16, 8) fp32
  float* out = (float*)d_out;              // (B, 10, 16) fp32

  const int batch = in_sizes[0] / (kN * kF);  // 256
  caps_routing_kernel<<<dim3(batch), dim3(kThreads), 0, stream>>>(x, W, out);
}

// Round 11
// 105.617 us; speedup vs baseline: 1.2528x; 1.1534x over previous
//
#include <hip/hip_runtime.h>
#include <math.h>

// CapsuleLayer dynamic routing, fully fused: one block per batch element.
// B=256, O=10, U=36, S=32, E=16, F=8, N=1152, 3 routing iterations.
//
// u_hat is never materialized:
//   v_pre[o,e]  = sum_{u,f} W[o,u,e,f] * cx[o,u,f],  cx[o,u,f] = sum_s c[o,n]*x[n,f]
//   b[o,n]     += sum_f x[n,f] * wv[o,u,f],          wv[o,u,f] = sum_e W[o,u,e,f]*v[o,e]
//
// Round-11: barrier-minimal schedule. Rounds 2-10 pinned the bottleneck on
// ~14 thin block-wide barrier phases (VALUBusy ~20% at 2 AND 4 waves/SIMD;
// occupancy and spill fixes orthogonal). This round: only the v-reduction is
// block-wide; wv/bsm/softmax/cx are WAVE-LOCAL (each u's 32 rows live in one
// half-wave, so the c that a wave's cx needs is produced by that same wave's
// bsm). 2 barriers/iter + prologue + epilogue = 8 total (was ~14).
// Wave-internal LDS write->read ordering: LDS is per-wave in-order; we add
// wave_barrier()+lgkmcnt(0) to stop compiler reordering.
//
// 512 threads = 8 waves (allocator-friendly per r7: 108 VGPR, no spill).
// Rows: n=t (u 0..15), n=512+t (u 16..31), and rows 1024..1151 on waves 2..5
// lanes 0..31 (u 32..35) -> wave u-counts {4,4,5,5,5,5,4,4}.
//
// LDS swizzles (proven r5/r7): u-stride is 32 rows -> 32*pitch = 0 mod 32
// banks for any pitch, so rotate slots by u:
//   x row (u,s), 16B half h' -> word u*256 + ((2s + h' + u)&63)*4
//   c[o][n]                  -> word o*1152 + u*32 + ((s+u)&31)

namespace {

constexpr int kO = 10;
constexpr int kU = 36;
constexpr int kS = 32;
constexpr int kE = 16;
constexpr int kF = 8;
constexpr int kN = kU * kS;   // 1152
constexpr int kIters = 3;
constexpr int kThreads = 512; // 8 waves, 2 per SIMD
constexpr int kPitch = 12;    // padded (o,u)-row pitch for s_cx/s_wv

// wave-internal LDS ordering fence (same-wave DS ops are HW-ordered; this
// stops the compiler from hoisting reads above writes)
#define WAVESYNC()                                              \
  do {                                                          \
    __builtin_amdgcn_wave_barrier();                            \
    asm volatile("s_waitcnt lgkmcnt(0)" ::: "memory");          \
    __builtin_amdgcn_wave_barrier();                            \
  } while (0)

__launch_bounds__(kThreads, 2)
__global__ void caps_routing_kernel(const float* __restrict__ xg,
                                    const float* __restrict__ Wg,
                                    float* __restrict__ outg) {
  __shared__ float s_x[kN * kF];            // 36.9 KB, swizzled
  __shared__ float s_c[kO * kN];            // 46.1 KB, swizzled
  __shared__ float s_cx[kO * kU * kPitch];  // 17.3 KB
  __shared__ float s_wv[kO * kU * kPitch];  // 17.3 KB
  __shared__ float s_vp[kO * kE * 3];       //  1.9 KB
  __shared__ float s_sx[kU * kF];           //  1.2 KB (sum_s x, for it=0)
  // total ~117.8 KB -> 1 block/CU

  const int t = threadIdx.x;
  const int w = t >> 6;
  const int l = t & 63;
  const int b = blockIdx.x;

  const bool five = (w >= 2 && w < 6);   // waves owning a u in 32..35
  const int nu = five ? 5 : 4;           // u's owned by this wave
  const bool has3 = five && (l < 32);    // lanes holding a third row

  // row geometry
  const int u0r = t >> 5;                // rows 0..511    -> u 0..15
  const int s0r = t & 31;
  const int rot0 = (s0r + u0r) & 31;
  const int u1r = 16 + (t >> 5);         // rows 512..1023 -> u 16..31
  const int rot1 = (s0r + u1r) & 31;
  const int u2r = 30 + w;                // rows 1024..1151 -> u 32..35 (w 2..5)
  const int rot2 = (l + u2r) & 31;

  float xr0[kF], xr1[kF], xr2[kF];
  float br0[kO], br1[kO], br2[kO];

  // ---- prologue: load rows -> regs + swizzled LDS; half-wave butterfly sx ----
#define STAGEROW(XR, N, U, S)                                                 \
  {                                                                           \
    const float4* src_ =                                                      \
        reinterpret_cast<const float4*>(xg + ((size_t)b * kN + (N)) * kF);    \
    const float4 a0_ = src_[0];                                               \
    const float4 a1_ = src_[1];                                               \
    XR[0] = a0_.x; XR[1] = a0_.y; XR[2] = a0_.z; XR[3] = a0_.w;               \
    XR[4] = a1_.x; XR[5] = a1_.y; XR[6] = a1_.z; XR[7] = a1_.w;               \
    const int sl0_ = (((S) << 1) + (U)) & 63;                                 \
    const int sl1_ = (((S) << 1) + 1 + (U)) & 63;                             \
    *reinterpret_cast<float4*>(&s_x[(U) * 256 + sl0_ * 4]) = a0_;             \
    *reinterpret_cast<float4*>(&s_x[(U) * 256 + sl1_ * 4]) = a1_;             \
    float4 r0_ = a0_, r1_ = a1_;                                              \
    _Pragma("unroll")                                                         \
    for (int m_ = 1; m_ <= 16; m_ <<= 1) {                                    \
      r0_.x += __shfl_xor(r0_.x, m_); r0_.y += __shfl_xor(r0_.y, m_);         \
      r0_.z += __shfl_xor(r0_.z, m_); r0_.w += __shfl_xor(r0_.w, m_);         \
      r1_.x += __shfl_xor(r1_.x, m_); r1_.y += __shfl_xor(r1_.y, m_);         \
      r1_.z += __shfl_xor(r1_.z, m_); r1_.w += __shfl_xor(r1_.w, m_);         \
    }                                                                         \
    if ((S) == 0) {                                                           \
      *reinterpret_cast<float4*>(&s_sx[(U) * kF + 0]) = r0_;                  \
      *reinterpret_cast<float4*>(&s_sx[(U) * kF + 4]) = r1_;                  \
    }                                                                         \
  }

  STAGEROW(xr0, t, u0r, s0r)
  STAGEROW(xr1, t + 512, u1r, s0r)
  if (has3) STAGEROW(xr2, 1024 + (w - 2) * 32 + l, u2r, l)
#undef STAGEROW
#pragma unroll
  for (int o = 0; o < kO; ++o) { br0[o] = 0.f; br1[o] = 0.f; br2[o] = 0.f; }
  __syncthreads();

  // wave's j-th owned u (j in 0..nu-1)
#define UOFJ(J) ((J) < 2 ? 2 * w + (J) : ((J) < 4 ? 14 + 2 * w + (J) : 30 + w))

  for (int it = 0; it <= kIters; ++it) {
    // ---- v_pre partials (block-wide): thread=(o,e,uc), 480 active ----
    if (l < 60) {
      const int i = w * 60 + l;  // 0..479
      const int o = i / 48;
      const int r = i - o * 48;
      const int e = r / 3;
      const int uc = r - e * 3;
      const int u0 = uc * 12;
      float accA = 0.f, accB = 0.f;
      const float* wrow = Wg + ((size_t)(o * kU + u0) * kE + e) * kF;
      if (it == 0) {
#pragma unroll 4
        for (int ui = 0; ui < 12; ++ui) {
          const float4* wp = reinterpret_cast<const float4*>(wrow);
          const float4 w0 = wp[0];
          const float4 w1 = wp[1];
          const float4* cp =
              reinterpret_cast<const float4*>(&s_sx[(u0 + ui) * kF]);
          const float4 c0 = cp[0];
          const float4 c1 = cp[1];
          accA += w0.x * c0.x + w0.y * c0.y + w0.z * c0.z + w0.w * c0.w;
          accB += w1.x * c1.x + w1.y * c1.y + w1.z * c1.z + w1.w * c1.w;
          wrow += kE * kF;
        }
        accA = (accA + accB) * 0.1f;
      } else {
#pragma unroll 4
        for (int ui = 0; ui < 12; ++ui) {
          const float4* wp = reinterpret_cast<const float4*>(wrow);
          const float4 w0 = wp[0];
          const float4 w1 = wp[1];
          const float4* cp = reinterpret_cast<const float4*>(
              &s_cx[(o * kU + u0 + ui) * kPitch]);
          const float4 c0 = cp[0];
          const float4 c1 = cp[1];
          accA += w0.x * c0.x + w0.y * c0.y + w0.z * c0.z + w0.w * c0.w;
          accB += w1.x * c1.x + w1.y * c1.y + w1.z * c1.z + w1.w * c1.w;
          wrow += kE * kF;
        }
        accA += accB;
      }
      s_vp[(o * kE + e) * 3 + uc] = accA;
    }
    __syncthreads();

    // ---- final pass: squash + store output, done ----
    if (it == kIters) {
      if (t < kO * kE) {
        const float vsum = s_vp[t * 3 + 0] + s_vp[t * 3 + 1] + s_vp[t * 3 + 2];
        float n2 = vsum * vsum;
#pragma unroll
        for (int m = 1; m <= 8; m <<= 1) n2 += __shfl_xor(n2, m);
        const float scale = sqrtf(n2) / (1.f + n2);
        outg[(size_t)b * kO * kE + t] = vsum * scale;
      }
      break;
    }

    // ================= wave-local interval: wv -> bsm -> cx =================

    // (a) wv for this wave's u's: roles l<40: o=l%10, q=l/10 -> fh=q&1, jp=q>>1
    if (l < 40) {
      const int o = l % 10;
      const int q = l / 10;
      const int fh = q & 1;
      const int jp = q >> 1;
      // rebuild v[o,:] + squash scale from s_vp (broadcast reads)
#define SUMVP(E_) (s_vp[(o * kE + (E_)) * 3 + 0] + \
                   s_vp[(o * kE + (E_)) * 3 + 1] + \
                   s_vp[(o * kE + (E_)) * 3 + 2])
      float4 va, vb, vc, vd;
      va.x = SUMVP(0);  va.y = SUMVP(1);  va.z = SUMVP(2);  va.w = SUMVP(3);
      vb.x = SUMVP(4);  vb.y = SUMVP(5);  vb.z = SUMVP(6);  vb.w = SUMVP(7);
      vc.x = SUMVP(8);  vc.y = SUMVP(9);  vc.z = SUMVP(10); vc.w = SUMVP(11);
      vd.x = SUMVP(12); vd.y = SUMVP(13); vd.z = SUMVP(14); vd.w = SUMVP(15);
#undef SUMVP
      const float n2 =
          va.x * va.x + va.y * va.y + va.z * va.z + va.w * va.w +
          vb.x * vb.x + vb.y * vb.y + vb.z * vb.z + vb.w * vb.w +
          vc.x * vc.x + vc.y * vc.y + vc.z * vc.z + vc.w * vc.w +
          vd.x * vd.x + vd.y * vd.y + vd.z * vd.z + vd.w * vd.w;
      const float scale = sqrtf(n2) / (1.f + n2);
      va.x *= scale; va.y *= scale; va.z *= scale; va.w *= scale;
      vb.x *= scale; vb.y *= scale; vb.z *= scale; vb.w *= scale;
      vc.x *= scale; vc.y *= scale; vc.z *= scale; vc.w *= scale;
      vd.x *= scale; vd.y *= scale; vd.z *= scale; vd.w *= scale;
      for (int j = jp; j < nu; j += 2) {
        const int u = UOFJ(j);
        const float* wbase =
            Wg + (size_t)((o * kU + u) * kE) * kF + fh * 4;
        float4 acc = make_float4(0.f, 0.f, 0.f, 0.f);
#define WSTEP(VE_, E_)                                                        \
  {                                                                           \
    const float4* wp =                                                        \
        reinterpret_cast<const float4*>(wbase + (E_) * kF);                   \
    const float4 w4 = wp[0];                                                  \
    acc.x += (VE_) * w4.x; acc.y += (VE_) * w4.y;                             \
    acc.z += (VE_) * w4.z; acc.w += (VE_) * w4.w;                             \
  }
        WSTEP(va.x, 0)  WSTEP(va.y, 1)  WSTEP(va.z, 2)  WSTEP(va.w, 3)
        WSTEP(vb.x, 4)  WSTEP(vb.y, 5)  WSTEP(vb.z, 6)  WSTEP(vb.w, 7)
        WSTEP(vc.x, 8)  WSTEP(vc.y, 9)  WSTEP(vc.z, 10) WSTEP(vc.w, 11)
        WSTEP(vd.x, 12) WSTEP(vd.y, 13) WSTEP(vd.z, 14) WSTEP(vd.w, 15)
#undef WSTEP
        *reinterpret_cast<float4*>(&s_wv[(o * kU + u) * kPitch + fh * 4]) = acc;
      }
    }
    WAVESYNC();  // wv (own wave) visible to bsm (own wave)

    // (b) bsm: b[o,n] += x.wv; thread-local softmax over o; write c to s_c
#define BSMROW(XR, BR, U, ROT)                                                \
  {                                                                           \
    float mx_ = -3.4e38f;                                                     \
    _Pragma("unroll")                                                         \
    for (int o_ = 0; o_ < kO; ++o_) {                                         \
      const float4* wp_ =                                                     \
          reinterpret_cast<const float4*>(&s_wv[(o_ * kU + (U)) * kPitch]);   \
      const float4 w0_ = wp_[0];                                              \
      const float4 w1_ = wp_[1];                                              \
      BR[o_] += w0_.x * XR[0] + w0_.y * XR[1] + w0_.z * XR[2] + w0_.w * XR[3] \
              + w1_.x * XR[4] + w1_.y * XR[5] + w1_.z * XR[6] + w1_.w * XR[7];\
      mx_ = fmaxf(mx_, BR[o_]);                                               \
    }                                                                         \
    float ex_[kO];                                                            \
    float sum_ = 0.f;                                                         \
    _Pragma("unroll")                                                         \
    for (int o_ = 0; o_ < kO; ++o_) {                                         \
      ex_[o_] = __expf(BR[o_] - mx_);                                         \
      sum_ += ex_[o_];                                                        \
    }                                                                         \
    const float inv_ = 1.f / sum_;                                            \
    _Pragma("unroll")                                                         \
    for (int o_ = 0; o_ < kO; ++o_)                                           \
      s_c[o_ * kN + (U) * 32 + (ROT)] = ex_[o_] * inv_;                       \
  }
    BSMROW(xr0, br0, u0r, rot0)
    BSMROW(xr1, br1, u1r, rot1)
    if (has3) BSMROW(xr2, br2, u2r, rot2)
#undef BSMROW
    WAVESYNC();  // c (own wave) visible to cx (own wave)

    // (c) cx for this wave's u's: roles l < nu*10: o = l%10, j = l/10
    if (l < nu * 10) {
      const int o = l % 10;
      const int j = l / 10;
      const int u = UOFJ(j);
      float4 p0 = make_float4(0.f, 0.f, 0.f, 0.f);
      float4 p1 = make_float4(0.f, 0.f, 0.f, 0.f);
      const float* cbase = &s_c[o * kN + u * 32];
      const float* xbase = &s_x[u * 256];
#pragma unroll 4
      for (int s = 0; s < kS; ++s) {
        const int rot = (s + u) & 31;
        const int sl0 = ((s << 1) + u) & 63;
        const int sl1 = ((s << 1) + 1 + u) & 63;
        const float4 xa = *reinterpret_cast<const float4*>(&xbase[sl0 * 4]);
        const float4 xb = *reinterpret_cast<const float4*>(&xbase[sl1 * 4]);
        const float c0 = cbase[rot];
        p0.x += c0 * xa.x; p0.y += c0 * xa.y; p0.z += c0 * xa.z; p0.w += c0 * xa.w;
        p1.x += c0 * xb.x; p1.y += c0 * xb.y; p1.z += c0 * xb.z; p1.w += c0 * xb.w;
      }
      float4* d = reinterpret_cast<float4*>(&s_cx[(o * kU + u) * kPitch]);
      d[0] = p0;
      d[1] = p1;
    }
    __syncthreads();  // s_cx visible to next v_pre (block-wide)
  }
#undef UOFJ
}

}  // namespace

extern "C" void kernel_launch(void* const* d_in, const int* in_sizes, int n_in,
                              void* d_out, int out_size, void* d_ws, size_t ws_size,
                              hipStream_t stream) {
  const float* x = (const float*)d_in[0];  // (B, 1152, 8) fp32
  const float* W = (const float*)d_in[1];  // (10, 36, 16, 8) fp32
  float* out = (float*)d_out;              // (B, 10, 16) fp32

  const int batch = in_sizes[0] / (kN * kF);  // 256
  caps_routing_kernel<<<dim3(batch), dim3(kThreads), 0, stream>>>(x, W, out);
}

// Round 13
// 98.330 us; speedup vs baseline: 1.3456x; 1.0741x over previous
//
#include <hip/hip_runtime.h>
#include <math.h>

// CapsuleLayer dynamic routing, fully fused: one block per batch element.
// B=256, O=10, U=36, S=32, E=16, F=8, N=1152, 3 routing iterations.
//
// u_hat is never materialized:
//   v_pre[o,e]  = sum_{u,f} W[o,u,e,f] * cx[o,u,f],  cx[o,u,f] = sum_s c[o,n]*x[n,f]
//   b[o,n]     += sum_f x[n,f] * wv[o,u,f],          wv[o,u,f] = sum_e W[o,u,e,f]*v[o,e]
//
// Round-13 = round-12 with the wave fence hardened (skill rule #18): r12
// failed ONLY on warm replays (first launch correct) — the schedule's
// dependency graph audits clean (all wv/bsm/cx edges same-wave, cross-wave
// edges __syncthreads-separated), so the leading cause is hipcc moving LDS
// ops across the inline-asm lgkmcnt despite the "memory" clobber.
// wave_barrier is a weaker hint; the documented fence is sched_barrier(0)
// on BOTH sides of the waitcnt.
//
// Schedule (r11): only the v-reduction is block-wide; wv/bsm/softmax/cx are
// WAVE-LOCAL (each u's 32 rows live in one half-wave, so the c a wave's cx
// needs is produced by that wave's own bsm). 2 block barriers/iter.
// Bank fixes (r12): s_c o-pitch 1153 (mod32=1), s_vp o-stride 49 (mod32=17),
// wv roles o=l/4 (quad lanes share o -> broadcast SUMVP), cx roles o=l/nu.
// 512 threads = 8 waves; rows: n=t (u 0..15), n=512+t (u 16..31), rows
// 1024..1151 on waves 2..5 lanes 0..31 -> wave u-counts {4,4,5,5,5,5,4,4}.
//
// LDS swizzles (r5/r7): u-stride is 32 rows -> 32*pitch = 0 mod 32 banks for
// any pitch, so rotate slots by u:
//   x row (u,s), 16B half h' -> word u*256 + ((2s + h' + u)&63)*4
//   c[o][n]                  -> word o*1153 + u*32 + ((s+u)&31)

namespace {

constexpr int kO = 10;
constexpr int kU = 36;
constexpr int kS = 32;
constexpr int kE = 16;
constexpr int kF = 8;
constexpr int kN = kU * kS;   // 1152
constexpr int kIters = 3;
constexpr int kThreads = 512; // 8 waves, 2 per SIMD
constexpr int kPitch = 12;    // padded (o,u)-row pitch for s_cx/s_wv
constexpr int kCP = 1153;     // s_c o-pitch (mod 32 = 1: conflict-free o-spread)
constexpr int kVP = 49;       // s_vp o-stride (mod 32 = 17)

// wave-internal LDS ordering fence. Rule #18: hipcc can hoist ops past an
// inline-asm s_waitcnt despite the "memory" clobber; sched_barrier(0) is the
// fence that actually pins scheduling. Same-wave DS ops complete in order and
// lgkmcnt(0) drains them, so after this fence this wave's prior LDS writes
// are visible to its subsequent LDS reads.
#define WAVESYNC()                                              \
  do {                                                          \
    __builtin_amdgcn_sched_barrier(0);                          \
    asm volatile("s_waitcnt lgkmcnt(0)" ::: "memory");          \
    __builtin_amdgcn_sched_barrier(0);                          \
  } while (0)

__launch_bounds__(kThreads, 2)
__global__ void caps_routing_kernel(const float* __restrict__ xg,
                                    const float* __restrict__ Wg,
                                    float* __restrict__ outg) {
  __shared__ float s_x[kN * kF];            // 36.9 KB, swizzled
  __shared__ float s_c[kO * kCP];           // 46.1 KB, swizzled + o-padded
  __shared__ float s_cx[kO * kU * kPitch];  // 17.3 KB
  __shared__ float s_wv[kO * kU * kPitch];  // 17.3 KB
  __shared__ float s_vp[kO * kVP];          //  2.0 KB (o-padded)
  __shared__ float s_sx[kU * kF];           //  1.2 KB (sum_s x, for it=0)
  // total ~118 KB -> 1 block/CU

  const int t = threadIdx.x;
  const int w = t >> 6;
  const int l = t & 63;
  const int b = blockIdx.x;

  const bool five = (w >= 2 && w < 6);   // waves owning a u in 32..35
  const int nu = five ? 5 : 4;           // u's owned by this wave
  const bool has3 = five && (l < 32);    // lanes holding a third row

  // row geometry
  const int u0r = t >> 5;                // rows 0..511    -> u 0..15
  const int s0r = t & 31;
  const int rot0 = (s0r + u0r) & 31;
  const int u1r = 16 + (t >> 5);         // rows 512..1023 -> u 16..31
  const int rot1 = (s0r + u1r) & 31;
  const int u2r = 30 + w;                // rows 1024..1151 -> u 32..35 (w 2..5)
  const int rot2 = (l + u2r) & 31;

  float xr0[kF], xr1[kF], xr2[kF];
  float br0[kO], br1[kO], br2[kO];

  // ---- prologue: load rows -> regs + swizzled LDS; half-wave butterfly sx ----
#define STAGEROW(XR, N, U, S)                                                 \
  {                                                                           \
    const float4* src_ =                                                      \
        reinterpret_cast<const float4*>(xg + ((size_t)b * kN + (N)) * kF);    \
    const float4 a0_ = src_[0];                                               \
    const float4 a1_ = src_[1];                                               \
    XR[0] = a0_.x; XR[1] = a0_.y; XR[2] = a0_.z; XR[3] = a0_.w;               \
    XR[4] = a1_.x; XR[5] = a1_.y; XR[6] = a1_.z; XR[7] = a1_.w;               \
    const int sl0_ = (((S) << 1) + (U)) & 63;                                 \
    const int sl1_ = (((S) << 1) + 1 + (U)) & 63;                             \
    *reinterpret_cast<float4*>(&s_x[(U) * 256 + sl0_ * 4]) = a0_;             \
    *reinterpret_cast<float4*>(&s_x[(U) * 256 + sl1_ * 4]) = a1_;             \
    float4 r0_ = a0_, r1_ = a1_;                                              \
    _Pragma("unroll")                                                         \
    for (int m_ = 1; m_ <= 16; m_ <<= 1) {                                    \
      r0_.x += __shfl_xor(r0_.x, m_); r0_.y += __shfl_xor(r0_.y, m_);         \
      r0_.z += __shfl_xor(r0_.z, m_); r0_.w += __shfl_xor(r0_.w, m_);         \
      r1_.x += __shfl_xor(r1_.x, m_); r1_.y += __shfl_xor(r1_.y, m_);         \
      r1_.z += __shfl_xor(r1_.z, m_); r1_.w += __shfl_xor(r1_.w, m_);         \
    }                                                                         \
    if ((S) == 0) {                                                           \
      *reinterpret_cast<float4*>(&s_sx[(U) * kF + 0]) = r0_;                  \
      *reinterpret_cast<float4*>(&s_sx[(U) * kF + 4]) = r1_;                  \
    }                                                                         \
  }

  STAGEROW(xr0, t, u0r, s0r)
  STAGEROW(xr1, t + 512, u1r, s0r)
  if (has3) STAGEROW(xr2, 1024 + (w - 2) * 32 + l, u2r, l)
#undef STAGEROW
#pragma unroll
  for (int o = 0; o < kO; ++o) { br0[o] = 0.f; br1[o] = 0.f; br2[o] = 0.f; }
  __syncthreads();

  // wave's j-th owned u (j in 0..nu-1)
#define UOFJ(J) ((J) < 2 ? 2 * w + (J) : ((J) < 4 ? 14 + 2 * w + (J) : 30 + w))

  for (int it = 0; it <= kIters; ++it) {
    // ---- v_pre partials (block-wide): thread=(o,e,uc), 480 active ----
    if (l < 60) {
      const int i = w * 60 + l;  // 0..479
      const int o = i / 48;
      const int r = i - o * 48;
      const int e = r / 3;
      const int uc = r - e * 3;
      const int u0 = uc * 12;
      float accA = 0.f, accB = 0.f;
      const float* wrow = Wg + ((size_t)(o * kU + u0) * kE + e) * kF;
      if (it == 0) {
#pragma unroll 4
        for (int ui = 0; ui < 12; ++ui) {
          const float4* wp = reinterpret_cast<const float4*>(wrow);
          const float4 w0 = wp[0];
          const float4 w1 = wp[1];
          const float4* cp =
              reinterpret_cast<const float4*>(&s_sx[(u0 + ui) * kF]);
          const float4 c0 = cp[0];
          const float4 c1 = cp[1];
          accA += w0.x * c0.x + w0.y * c0.y + w0.z * c0.z + w0.w * c0.w;
          accB += w1.x * c1.x + w1.y * c1.y + w1.z * c1.z + w1.w * c1.w;
          wrow += kE * kF;
        }
        accA = (accA + accB) * 0.1f;
      } else {
#pragma unroll 4
        for (int ui = 0; ui < 12; ++ui) {
          const float4* wp = reinterpret_cast<const float4*>(wrow);
          const float4 w0 = wp[0];
          const float4 w1 = wp[1];
          const float4* cp = reinterpret_cast<const float4*>(
              &s_cx[(o * kU + u0 + ui) * kPitch]);
          const float4 c0 = cp[0];
          const float4 c1 = cp[1];
          accA += w0.x * c0.x + w0.y * c0.y + w0.z * c0.z + w0.w * c0.w;
          accB += w1.x * c1.x + w1.y * c1.y + w1.z * c1.z + w1.w * c1.w;
          wrow += kE * kF;
        }
        accA += accB;
      }
      s_vp[o * kVP + e * 3 + uc] = accA;
    }
    __syncthreads();

    // ---- final pass: squash + store output, done ----
    if (it == kIters) {
      if (t < kO * kE) {
        const int o = t >> 4;
        const int e = t & 15;
        const float vsum = s_vp[o * kVP + e * 3 + 0] +
                           s_vp[o * kVP + e * 3 + 1] +
                           s_vp[o * kVP + e * 3 + 2];
        float n2 = vsum * vsum;
#pragma unroll
        for (int m = 1; m <= 8; m <<= 1) n2 += __shfl_xor(n2, m);
        const float scale = sqrtf(n2) / (1.f + n2);
        outg[(size_t)b * kO * kE + t] = vsum * scale;
      }
      break;
    }

    // ================= wave-local interval: wv -> bsm -> cx =================

    // (a) wv for this wave's u's: roles l<40: o=l/4 (slow), q=l%4 -> fh,jp.
    // Quad lanes share o -> SUMVP reads are broadcast; across quads o-stride
    // 49 mod 32 = 17 -> distinct banks.
    if (l < 40) {
      const int o = l >> 2;
      const int q = l & 3;
      const int fh = q & 1;
      const int jp = q >> 1;
      // rebuild v[o,:] + squash scale from s_vp (broadcast reads)
#define SUMVP(E_) (s_vp[o * kVP + (E_) * 3 + 0] + \
                   s_vp[o * kVP + (E_) * 3 + 1] + \
                   s_vp[o * kVP + (E_) * 3 + 2])
      float4 va, vb, vc, vd;
      va.x = SUMVP(0);  va.y = SUMVP(1);  va.z = SUMVP(2);  va.w = SUMVP(3);
      vb.x = SUMVP(4);  vb.y = SUMVP(5);  vb.z = SUMVP(6);  vb.w = SUMVP(7);
      vc.x = SUMVP(8);  vc.y = SUMVP(9);  vc.z = SUMVP(10); vc.w = SUMVP(11);
      vd.x = SUMVP(12); vd.y = SUMVP(13); vd.z = SUMVP(14); vd.w = SUMVP(15);
#undef SUMVP
      const float n2 =
          va.x * va.x + va.y * va.y + va.z * va.z + va.w * va.w +
          vb.x * vb.x + vb.y * vb.y + vb.z * vb.z + vb.w * vb.w +
          vc.x * vc.x + vc.y * vc.y + vc.z * vc.z + vc.w * vc.w +
          vd.x * vd.x + vd.y * vd.y + vd.z * vd.z + vd.w * vd.w;
      const float scale = sqrtf(n2) / (1.f + n2);
      va.x *= scale; va.y *= scale; va.z *= scale; va.w *= scale;
      vb.x *= scale; vb.y *= scale; vb.z *= scale; vb.w *= scale;
      vc.x *= scale; vc.y *= scale; vc.z *= scale; vc.w *= scale;
      vd.x *= scale; vd.y *= scale; vd.z *= scale; vd.w *= scale;
      for (int j = jp; j < nu; j += 2) {
        const int u = UOFJ(j);
        const float* wbase =
            Wg + (size_t)((o * kU + u) * kE) * kF + fh * 4;
        float4 acc = make_float4(0.f, 0.f, 0.f, 0.f);
#define WSTEP(VE_, E_)                                                        \
  {                                                                           \
    const float4* wp =                                                        \
        reinterpret_cast<const float4*>(wbase + (E_) * kF);                   \
    const float4 w4 = wp[0];                                                  \
    acc.x += (VE_) * w4.x; acc.y += (VE_) * w4.y;                             \
    acc.z += (VE_) * w4.z; acc.w += (VE_) * w4.w;                             \
  }
        WSTEP(va.x, 0)  WSTEP(va.y, 1)  WSTEP(va.z, 2)  WSTEP(va.w, 3)
        WSTEP(vb.x, 4)  WSTEP(vb.y, 5)  WSTEP(vb.z, 6)  WSTEP(vb.w, 7)
        WSTEP(vc.x, 8)  WSTEP(vc.y, 9)  WSTEP(vc.z, 10) WSTEP(vc.w, 11)
        WSTEP(vd.x, 12) WSTEP(vd.y, 13) WSTEP(vd.z, 14) WSTEP(vd.w, 15)
#undef WSTEP
        *reinterpret_cast<float4*>(&s_wv[(o * kU + u) * kPitch + fh * 4]) = acc;
      }
    }
    WAVESYNC();  // wv (own wave) visible to bsm (own wave)

    // (b) bsm: b[o,n] += x.wv; thread-local softmax over o; write c to s_c
#define BSMROW(XR, BR, U, ROT)                                                \
  {                                                                           \
    float mx_ = -3.4e38f;                                                     \
    _Pragma("unroll")                                                         \
    for (int o_ = 0; o_ < kO; ++o_) {                                         \
      const float4* wp_ =                                                     \
          reinterpret_cast<const float4*>(&s_wv[(o_ * kU + (U)) * kPitch]);   \
      const float4 w0_ = wp_[0];                                              \
      const float4 w1_ = wp_[1];                                              \
      BR[o_] += w0_.x * XR[0] + w0_.y * XR[1] + w0_.z * XR[2] + w0_.w * XR[3] \
              + w1_.x * XR[4] + w1_.y * XR[5] + w1_.z * XR[6] + w1_.w * XR[7];\
      mx_ = fmaxf(mx_, BR[o_]);                                               \
    }                                                                         \
    float ex_[kO];                                                            \
    float sum_ = 0.f;                                                         \
    _Pragma("unroll")                                                         \
    for (int o_ = 0; o_ < kO; ++o_) {                                         \
      ex_[o_] = __expf(BR[o_] - mx_);                                         \
      sum_ += ex_[o_];                                                        \
    }                                                                         \
    const float inv_ = 1.f / sum_;                                            \
    _Pragma("unroll")                                                         \
    for (int o_ = 0; o_ < kO; ++o_)                                           \
      s_c[o_ * kCP + (U) * 32 + (ROT)] = ex_[o_] * inv_;                      \
  }
    BSMROW(xr0, br0, u0r, rot0)
    BSMROW(xr1, br1, u1r, rot1)
    if (has3) BSMROW(xr2, br2, u2r, rot2)
#undef BSMROW
    WAVESYNC();  // c (own wave) visible to cx (own wave)

    // (c) cx for this wave's u's: roles l < 10*nu: o = l/nu (slow), j = l%nu.
    // s_c reads: bank = (o + (s+u)) mod 32 across lanes -> spread.
    if (l < kO * nu) {
      const int o = l / nu;
      const int j = l - o * nu;
      const int u = UOFJ(j);
      float4 p0 = make_float4(0.f, 0.f, 0.f, 0.f);
      float4 p1 = make_float4(0.f, 0.f, 0.f, 0.f);
      const float* cbase = &s_c[o * kCP + u * 32];
      const float* xbase = &s_x[u * 256];
#pragma unroll 4
      for (int s = 0; s < kS; ++s) {
        const int rot = (s + u) & 31;
        const int sl0 = ((s << 1) + u) & 63;
        const int sl1 = ((s << 1) + 1 + u) & 63;
        const float4 xa = *reinterpret_cast<const float4*>(&xbase[sl0 * 4]);
        const float4 xb = *reinterpret_cast<const float4*>(&xbase[sl1 * 4]);
        const float c0 = cbase[rot];
        p0.x += c0 * xa.x; p0.y += c0 * xa.y; p0.z += c0 * xa.z; p0.w += c0 * xa.w;
        p1.x += c0 * xb.x; p1.y += c0 * xb.y; p1.z += c0 * xb.z; p1.w += c0 * xb.w;
      }
      float4* d = reinterpret_cast<float4*>(&s_cx[(o * kU + u) * kPitch]);
      d[0] = p0;
      d[1] = p1;
    }
    __syncthreads();  // s_cx visible to next v_pre (block-wide)
  }
#undef UOFJ
}

}  // namespace

extern "C" void kernel_launch(void* const* d_in, const int* in_sizes, int n_in,
                              void* d_out, int out_size, void* d_ws, size_t ws_size,
                              hipStream_t stream) {
  const float* x = (const float*)d_in[0];  // (B, 1152, 8) fp32
  const float* W = (const float*)d_in[1];  // (10, 36, 16, 8) fp32
  float* out = (float*)d_out;              // (B, 10, 16) fp32

  const int batch = in_sizes[0] / (kN * kF);  // 256
  caps_routing_kernel<<<dim3(batch), dim3(kThreads), 0, stream>>>(x, W, out);
}